// Round 5
// baseline (39.539 us; speedup 1.0000x reference)
//
#include <hip/hip_runtime.h>
#include <stdint.h>

// CorrelationLayer: out[b, i*41+j, y, x] = sum_c f1[b,c,y,x]*f2[b,c,y+i-20,x+j-20]
// R5: two-kernel plan (pre-convert bf16 + banded MFMA), same as R4 except:
//  - ALL stores are plain (no nontemporal): the XCD swizzle puts 32 adjacent-y
//    blocks on one XCD, so per (di,k) plane L2 receives 32 x 256B consecutive
//    segments = 8KB; normal stores let L2 merge them into full DRAM bursts
//    (nt hints blocked retention -> 256B islands -> ~50% write BW).
//  - conv_kernel at 1024 blocks (2 c-groups/thread) for latency.

#define NB 4
#define NC 128
#define NH 64
#define NW 64
#define PAD 20
#define ND 41
#define HW (NH * NW)
#define ROW_U4 1024  // 16 q-groups * 64 x per (b,y) row, in uint4 units

typedef __attribute__((ext_vector_type(8))) __bf16 bf16x8;
typedef __attribute__((ext_vector_type(16))) float f32x16;

__device__ __forceinline__ unsigned int pk2(float a, float b) {
  // folds to v_cvt_pk_bf16_f32 (RNE)
  unsigned short lo = __builtin_bit_cast(unsigned short, (__bf16)a);
  unsigned short hi = __builtin_bit_cast(unsigned short, (__bf16)b);
  return (unsigned int)lo | ((unsigned int)hi << 16);
}

// ---------------- kernel 1: fp32 -> bf16 repack --------------------------
// f_t[((b*64+y)*16 + q)*64 + x] (uint4) = channels 8q..8q+7 at (y,x), bf16.
__global__ __launch_bounds__(256) void conv_kernel(
    const float* __restrict__ f1, const float* __restrict__ f2,
    uint4* __restrict__ ws) {
  const int blk = blockIdx.x;  // 0..1023
  const int isF2 = blk >> 9;
  const int by = (blk >> 1) & 255;  // b*64+y
  const int chalf = blk & 1;
  const int b = by >> 6, y = by & 63;
  const float* src = (isF2 ? f2 : f1) + (size_t)b * NC * HW + (size_t)y * NW;
  uint4* dst = ws + (size_t)isF2 * (NB * NH * ROW_U4) + (size_t)by * ROW_U4;
  const int x = threadIdx.x & 63;   // 64 lanes consecutive x = 256B segments
  const int cq = threadIdx.x >> 6;  // 0..3
#pragma unroll
  for (int it = 0; it < 2; ++it) {
    const int cg = chalf * 8 + it * 4 + cq;
    float v[8];
#pragma unroll
    for (int i = 0; i < 8; ++i) v[i] = src[(size_t)(cg * 8 + i) * HW + x];
    uint4 u;
    u.x = pk2(v[0], v[1]);
    u.y = pk2(v[2], v[3]);
    u.z = pk2(v[4], v[5]);
    u.w = pk2(v[6], v[7]);
    dst[cg * 64 + x] = u;  // 1KB contiguous per wave; ws is L2-resident
  }
}

// ---------------- kernel 2: banded MFMA correlation -----------------------
__global__ __launch_bounds__(256, 4) void corr_main(
    const uint4* __restrict__ ws, float* __restrict__ out) {
  __shared__ float cbuf[2][64 * 64];  // 32 KB total -> 4 blocks/CU

  // XCD swizzle: 1024 blocks, 128/XCD chunk; dq fastest then y -> each XCD
  // owns a 32-wide y band (f2t slice ~1.2MB L2-resident) and its stores for
  // any (di,k) plane form 32x256B consecutive-y segments that merge in L2.
  const int bid = blockIdx.x;
  const int lid = (bid & 7) * 128 + (bid >> 3);
  const int dq = lid & 3;
  const int y = (lid >> 2) & 63;
  const int b = lid >> 8;

  const int t = threadIdx.x;
  const int lane = t & 63;
  const int wv = t >> 6;  // wave -> 32x32 C tile (I=row half, J=col half)
  const int I = wv & 1;
  const int J = wv >> 1;
  const int kh = lane >> 5;

  // mfma_f32_32x32x16_bf16: A row = lane&31 (+32I), B col = lane&31 (+32J),
  // frag ks = channels 16ks+8kh..+8 -> q = 2ks+kh.
  // C/D: col = lane&31 (+32J), row = 32I + 4kh + (r&3) + 8*(r>>2).
  const int xa = I * 32 + (lane & 31);
  const int xb = J * 32 + (lane & 31);
  const int col = (lane & 31) + 32 * J;
  const int rbase = kh * 4 + I * 32;
  const int xg = t & 63;  // extract/store mapping
  const int g = t >> 6;

  const uint4* f1t = ws;
  const uint4* f2t = ws + NB * NH * ROW_U4;

  const int dBeg = (ND * dq) / 4;        // 0,10,20,30
  const int dEnd = (ND * (dq + 1)) / 4;  // 10,20,30,41
  // valid di: 0 <= y+di-20 < 64  ->  di in [20-y, 84-y)
  int a0 = 20 - y;
  if (a0 < dBeg) a0 = dBeg;
  if (a0 > dEnd) a0 = dEnd;
  int a1 = 84 - y;
  if (a1 < a0) a1 = a0;
  if (a1 > dEnd) a1 = dEnd;

  const size_t outBase = (size_t)b * (ND * ND) * HW + (size_t)y * NW;

  // zero planes: [dBeg,a0) and [a1,dEnd)
  for (int di = dBeg; di < a0; ++di) {
    const size_t dB = outBase + (size_t)di * ND * HW;
    for (int k = g; k < ND; k += 4) out[dB + (size_t)k * HW + xg] = 0.f;
  }
  for (int di = a1; di < dEnd; ++di) {
    const size_t dB = outBase + (size_t)di * ND * HW;
    for (int k = g; k < ND; k += 4) out[dB + (size_t)k * HW + xg] = 0.f;
  }
  const int n = a1 - a0;
  if (n <= 0) return;

  // loop-invariant B fragments (f1 row y), 8x dwordx4
  const uint4* f1row = f1t + (size_t)(b * 64 + y) * ROW_U4 + kh * 64 + xb;
  bf16x8 bfrag[8];
#pragma unroll
  for (int ks = 0; ks < 8; ++ks)
    bfrag[ks] = __builtin_bit_cast(bf16x8, f1row[ks * 128]);

  const uint4* f2row = f2t + (size_t)(b * 64) * ROW_U4 + kh * 64 + xa;

  int p = 0;
#pragma unroll 1
  for (int j = 0; j < n; ++j) {
    const int yp = y + (a0 + j) - PAD;
    const uint4* ap = f2row + (size_t)yp * ROW_U4;
    uint4 a[8];  // A fragments for this di, issued first
#pragma unroll
    for (int ks = 0; ks < 8; ++ks) a[ks] = ap[ks * 128];

    if (j > 0) {  // lag-extract previous C while A loads are in flight
      const size_t dB = outBase + (size_t)(a0 + j - 1) * ND * HW;
      const float* cb = cbuf[p ^ 1];
      for (int k = g; k < ND; k += 4) {
        const int xs = xg + k - PAD;
        const float vv = (xs >= 0 && xs < NW) ? cb[xs * 64 + xg] : 0.f;
        out[dB + (size_t)k * HW + xg] = vv;
      }
    }

    f32x16 acc;
#pragma unroll
    for (int r = 0; r < 16; ++r) acc[r] = 0.f;
#pragma unroll
    for (int ks = 0; ks < 8; ++ks)
      acc = __builtin_amdgcn_mfma_f32_32x32x16_bf16(
          __builtin_bit_cast(bf16x8, a[ks]), bfrag[ks], acc, 0, 0, 0);
#pragma unroll
    for (int r = 0; r < 16; ++r) {
      const int row = rbase + (r & 3) + 8 * (r >> 2);
      cbuf[p][row * 64 + col] = acc[r];  // banks 0..31 per half-wave: free
    }
    __syncthreads();  // cbuf[p] ready; prior extract reads drained
    p ^= 1;
  }

  {  // epilogue extract
    const size_t dB = outBase + (size_t)(a0 + n - 1) * ND * HW;
    const float* cb = cbuf[p ^ 1];
    for (int k = g; k < ND; k += 4) {
      const int xs = xg + k - PAD;
      const float vv = (xs >= 0 && xs < NW) ? cb[xs * 64 + xg] : 0.f;
      out[dB + (size_t)k * HW + xg] = vv;
    }
  }
}

// ---------------- fallback (single-kernel path, no ws) --------------------
__device__ __forceinline__ float f4elem(const float4 v, int j) {
  return j == 0 ? v.x : j == 1 ? v.y : j == 2 ? v.z : v.w;
}

__device__ __forceinline__ void convwrite(const float4 (&v)[8],
                                          uint4* __restrict__ lds, int xq,
                                          int cg) {
#pragma unroll
  for (int j = 0; j < 4; ++j) {
    const int x = xq * 4 + j;
    uint4 u;
    u.x = pk2(f4elem(v[0], j), f4elem(v[1], j));
    u.y = pk2(f4elem(v[2], j), f4elem(v[3], j));
    u.z = pk2(f4elem(v[4], j), f4elem(v[5], j));
    u.w = pk2(f4elem(v[6], j), f4elem(v[7], j));
    lds[x * 16 + (cg ^ (x & 7))] = u;
  }
}

__global__ __launch_bounds__(256, 2) void corr_fallback(
    const float* __restrict__ feat1, const float* __restrict__ feat2,
    float* __restrict__ out) {
  __shared__ uint4 f2s[2][64 * 16];
  __shared__ float cbuf[2][64 * 64];

  const int bid = blockIdx.x;
  const int lid = (bid & 7) * 64 + (bid >> 3);
  const int half = lid & 1;
  const int y = (lid >> 1) & 63;
  const int b = lid >> 7;

  const int t = threadIdx.x;
  const int lane = t & 63;
  const int wv = t >> 6;
  const int I = wv & 1;
  const int J = wv >> 1;
  const int xa = I * 32 + (lane & 31);
  const int xb = J * 32 + (lane & 31);
  const int kh = lane >> 5;
  const int aBase = xa * 16, aSw = xa & 7;
  const int bBase = xb * 16, bSw = xb & 7;
  const int col = (lane & 31) + J * 32;
  const int rbase = kh * 4 + I * 32;
  const int xg = t & 63;
  const int g = t >> 6;
  const int xq = t & 15;
  const int cg = t >> 4;
  const size_t rowoff = (size_t)cg * 8 * HW + xq * 4;
  const float* f1row = feat1 + (size_t)b * NC * HW + (size_t)y * NW + rowoff;
  const float* f2row0 = feat2 + (size_t)b * NC * HW + rowoff;
  const size_t outBase = ((size_t)b * (ND * ND) * NH + y) * NW;

  int dBeg, dEnd;
  if (half == 0) {
    dBeg = (y < PAD) ? (PAD - y) : 0;
    dEnd = PAD + 1;
  } else {
    dBeg = PAD + 1;
    const int e = (NH + PAD) - y;
    dEnd = e < ND ? e : ND;
  }
  const int zBeg = half ? dEnd : 0;
  const int zEnd = half ? ND : dBeg;
  for (int di = zBeg; di < zEnd; ++di) {
    const size_t dB = outBase + (size_t)di * ND * HW;
    for (int k = g; k < ND; k += 4) out[dB + (size_t)k * HW + xg] = 0.f;
  }
  if (dBeg >= dEnd) return;

  float4 v[8];
#pragma unroll
  for (int i = 0; i < 8; ++i) v[i] = *(const float4*)(f1row + (size_t)i * HW);
  uint4* f1tmp = (uint4*)&cbuf[0][0];
  convwrite(v, f1tmp, xq, cg);
  {
    const int yp0 = y + dBeg - PAD;
#pragma unroll
    for (int i = 0; i < 8; ++i)
      v[i] = *(const float4*)(f2row0 + (size_t)yp0 * NW + (size_t)i * HW);
  }
  __syncthreads();
  bf16x8 bfrag[8];
#pragma unroll
  for (int ks = 0; ks < 8; ++ks) {
    const int q = ks * 2 + kh;
    bfrag[ks] = __builtin_bit_cast(bf16x8, f1tmp[bBase + (q ^ bSw)]);
  }
  __syncthreads();

  const int nIter = dEnd - dBeg;
  int p = 0;
#pragma unroll 1
  for (int j = 0; j < nIter; ++j) {
    convwrite(v, f2s[p], xq, cg);
    {
      const int nj = (j + 1 < nIter) ? j + 1 : j;
      const int ypn = y + dBeg + nj - PAD;
#pragma unroll
      for (int i = 0; i < 8; ++i)
        v[i] = *(const float4*)(f2row0 + (size_t)ypn * NW + (size_t)i * HW);
    }
    __syncthreads();

    f32x16 acc;
#pragma unroll
    for (int r = 0; r < 16; ++r) acc[r] = 0.f;
#pragma unroll
    for (int ks = 0; ks < 8; ++ks) {
      const int q = ks * 2 + kh;
      bf16x8 aa = __builtin_bit_cast(bf16x8, f2s[p][aBase + (q ^ aSw)]);
      acc = __builtin_amdgcn_mfma_f32_32x32x16_bf16(aa, bfrag[ks], acc, 0, 0, 0);
    }
#pragma unroll
    for (int r = 0; r < 16; ++r) {
      const int row = rbase + (r & 3) + 8 * (r >> 2);
      cbuf[p][row * 64 + col] = acc[r];
    }
    if (j > 0) {
      const size_t dBase = outBase + (size_t)(dBeg + j - 1) * ND * HW;
      const float* cb = cbuf[p ^ 1];
      for (int k = g; k < ND; k += 4) {
        const int xs = xg + k - PAD;
        const float vv = (xs >= 0 && xs < NW) ? cb[xs * 64 + xg] : 0.f;
        out[dBase + (size_t)k * HW + xg] = vv;
      }
    }
    p ^= 1;
  }
  __syncthreads();
  {
    const size_t dBase = outBase + (size_t)(dEnd - 1) * ND * HW;
    const float* cb = cbuf[p ^ 1];
    for (int k = g; k < ND; k += 4) {
      const int xs = xg + k - PAD;
      const float vv = (xs >= 0 && xs < NW) ? cb[xs * 64 + xg] : 0.f;
      out[dBase + (size_t)k * HW + xg] = vv;
    }
  }
}

extern "C" void kernel_launch(void* const* d_in, const int* in_sizes, int n_in,
                              void* d_out, int out_size, void* d_ws,
                              size_t ws_size, hipStream_t stream) {
  (void)in_sizes; (void)n_in; (void)out_size;
  const float* f1 = (const float*)d_in[0];
  const float* f2 = (const float*)d_in[1];
  float* out = (float*)d_out;
  const size_t need = (size_t)2 * NB * NH * ROW_U4 * sizeof(uint4);  // 8 MB
  if (ws_size >= need && d_ws != nullptr) {
    uint4* ws = (uint4*)d_ws;
    conv_kernel<<<dim3(1024), dim3(256), 0, stream>>>(f1, f2, ws);
    corr_main<<<dim3(NB * NH * 4), dim3(256), 0, stream>>>(ws, out);
  } else {
    corr_fallback<<<dim3(NB * NH * 2), dim3(256), 0, stream>>>(f1, f2, out);
  }
}